// Round 7
// baseline (994.368 us; speedup 1.0000x reference)
//
#include <hip/hip_runtime.h>
#include <hip/hip_cooperative_groups.h>
#include <cstdint>

namespace cg = cooperative_groups;

typedef __attribute__((ext_vector_type(8))) short short8;
typedef __attribute__((ext_vector_type(4))) float f32x4;

static __device__ __forceinline__ unsigned short f2bf(float f) {
  unsigned int u = __float_as_uint(f);
  unsigned int r = (u + 0x7FFFu + ((u >> 16) & 1u)) >> 16;   // RNE
  return (unsigned short)r;
}
static __device__ __forceinline__ unsigned int pack2bf(float a, float b) {
  return (unsigned int)f2bf(a) | ((unsigned int)f2bf(b) << 16);
}
static __device__ __forceinline__ float2 bf2f(unsigned int u) {
  return make_float2(__uint_as_float(u << 16), __uint_as_float(u & 0xFFFF0000u));
}
static __device__ __forceinline__ void acc8(float* a, uint4 h, uint4 r) {
  float2 f, g;
  f = bf2f(h.x); g = bf2f(r.x); a[0] += f.x - g.x; a[1] += f.y - g.y;
  f = bf2f(h.y); g = bf2f(r.y); a[2] += f.x - g.x; a[3] += f.y - g.y;
  f = bf2f(h.z); g = bf2f(r.z); a[4] += f.x - g.x; a[5] += f.y - g.y;
  f = bf2f(h.w); g = bf2f(r.w); a[6] += f.x - g.x; a[7] += f.y - g.y;
}

// ---- one-shot prep kernel (unchanged from R5) ----
__global__ __launch_bounds__(256) void k_prep(
    const float* __restrict__ coeff, const float* __restrict__ bases,
    const float* __restrict__ selfr, const float* __restrict__ relw1,
    const float* __restrict__ relw2,
    unsigned int* __restrict__ rfb, unsigned int* __restrict__ r1b,
    float* __restrict__ r2,
    const float* __restrict__ W1, const float* __restrict__ W2,
    unsigned short* __restrict__ WT1, unsigned short* __restrict__ WT2,
    const float* __restrict__ ent, const int* __restrict__ ent_ids,
    unsigned int* __restrict__ entbf,
    int* __restrict__ counts, float* __restrict__ stats,
    int nPairs, int nKeys, int cvtB, int cntB) {
  int b = blockIdx.x, tid = threadIdx.x;
  if (b < 201) {
    __shared__ float row[2][128], r1row[2][128];
    int half = tid >> 7, c = tid & 127;
    int r = 2 * b + half;
    bool ok = (r <= 400);
    if (ok) {
      float v;
      if (r == 400) {
        v = selfr[c];
      } else {
        int rr = (r < 200) ? r : r - 200;
        float s = 0.f;
#pragma unroll 10
        for (int k = 0; k < 50; ++k) s += coeff[rr * 50 + k] * bases[k * 128 + c];
        v = (r < 200) ? s : -s;
      }
      row[half][c] = v;
    }
    __syncthreads();
    if (ok && c < 64) rfb[r * 64 + c] = pack2bf(row[half][2 * c], row[half][2 * c + 1]);
    if (ok) {
      float s = 0.f;
#pragma unroll 8
      for (int k = 0; k < 128; ++k) s += row[half][k] * relw1[k * 128 + c];
      r1row[half][c] = s;
    }
    __syncthreads();
    if (ok && c < 64) r1b[r * 64 + c] = pack2bf(r1row[half][2 * c], r1row[half][2 * c + 1]);
    if (ok) {
      float s = 0.f;
#pragma unroll 8
      for (int k = 0; k < 128; ++k) s += r1row[half][k] * relw2[k * 128 + c];
      r2[r * 128 + c] = s;
    }
  } else if (b < 585) {
    int idx = (b - 201) * 256 + tid;
    const int half = 128 * 384;
    const float* W = (idx < half) ? W1 : W2;
    unsigned short* WT = (idx < half) ? WT1 : WT2;
    int id2 = (idx < half) ? idx : idx - half;
    int n = id2 & 127, k = id2 >> 7;
    int kk = k >> 7, kr = k & 127;
    WT[(size_t)n * 384 + k] = f2bf(W[(size_t)kk * 16384 + kr * 128 + n]);
  } else if (b < 585 + cvtB) {
    int i = (b - 585) * 256 + tid;
    if (i < nPairs) {
      int e = i >> 6;
      int src = ent_ids[e];
      float2 v = *(const float2*)&ent[(size_t)src * 128 + (i & 63) * 2];
      entbf[i] = pack2bf(v.x, v.y);
    }
  } else if (b < 585 + cvtB + cntB) {
    int i = (b - (585 + cvtB)) * 256 + tid;
    if (i < nKeys) counts[i] = 0;
  } else {
    int i = (b - (585 + cvtB + cntB)) * 256 + tid;
    if (i < 16896) stats[i] = 0.f;
  }
}

// ---- CSR build (unchanged, range-partitioned) ----
__global__ __launch_bounds__(256) void k_histR(const int* __restrict__ ei, const int* __restrict__ y,
                                               int* __restrict__ counts, int nE, int rsz) {
  int r = blockIdx.x;
  int e0 = blockIdx.y * 1024;
#pragma unroll
  for (int i = 0; i < 4; ++i) {
    int e = e0 + i * 256 + threadIdx.x;
    if (e < nE) {
      int key = ei[nE + e] * 3 + y[e];
      if (key / rsz == r) atomicAdd(&counts[key], 1);
    }
  }
}

__global__ void k_scan1(const int* __restrict__ counts, int* __restrict__ local,
                        int* __restrict__ blockSums, int n) {
  __shared__ int sdata[1024];
  int tid = threadIdx.x;
  int i = blockIdx.x * 1024 + tid;
  int v = (i < n) ? counts[i] : 0;
  sdata[tid] = v;
  __syncthreads();
  for (int off = 1; off < 1024; off <<= 1) {
    int t = (tid >= off) ? sdata[tid - off] : 0;
    __syncthreads();
    sdata[tid] += t;
    __syncthreads();
  }
  if (i < n) local[i] = sdata[tid] - v;
  if (tid == 1023) blockSums[blockIdx.x] = sdata[1023];
}

__global__ void k_scan2(const int* __restrict__ blockSums, int* __restrict__ carries,
                        int* __restrict__ offsets, int n, int nb) {
  __shared__ int sdata[1024];
  int tid = threadIdx.x;
  int v = (tid < nb) ? blockSums[tid] : 0;
  sdata[tid] = v;
  __syncthreads();
  for (int off = 1; off < 1024; off <<= 1) {
    int t = (tid >= off) ? sdata[tid - off] : 0;
    __syncthreads();
    sdata[tid] += t;
    __syncthreads();
  }
  if (tid < nb) carries[tid] = sdata[tid] - v;
  if (tid == 1023) offsets[n] = sdata[1023];
}

__global__ void k_scan3(const int* __restrict__ local, const int* __restrict__ carries,
                        int* __restrict__ offsets, int* __restrict__ cursor, int n) {
  int i = blockIdx.x * 1024 + threadIdx.x;
  if (i >= n) return;
  int v = local[i] + carries[blockIdx.x];
  offsets[i] = v;
  cursor[i] = v;
}

__global__ __launch_bounds__(256) void k_fillR(const int* __restrict__ ei, const int* __restrict__ et,
                                               const int* __restrict__ y, int* __restrict__ cursor,
                                               unsigned int* __restrict__ bucket, int nE, int rsz) {
  int r = blockIdx.x;
  int e0 = blockIdx.y * 1024;
#pragma unroll
  for (int i = 0; i < 4; ++i) {
    int e = e0 + i * 256 + threadIdx.x;
    if (e < nE) {
      int key = ei[nE + e] * 3 + y[e];
      if (key / rsz == r) {
        int slot = atomicAdd(&cursor[key], 1);
        bucket[slot] = (unsigned int)ei[e] | ((unsigned int)et[e] << 20);
      }
    }
  }
}

// ---- shared gather: 16 quad-groups x 6 keys -> As[32][392] (R5-verified) ----
static __device__ __forceinline__ void gather96(
    const unsigned int* __restrict__ xb, const unsigned int* __restrict__ rb,
    const int* __restrict__ offsets, const unsigned int* __restrict__ packed,
    unsigned short (*As)[392], int m0, int qid, int l16) {
#pragma unroll 1
  for (int i = 0; i < 6; ++i) {
    int kloc = qid * 6 + i;                  // 0..95
    int dloc = kloc / 3, cls = kloc - dloc * 3;
    float a0[8] = {}, a1[8] = {};
    int key = (m0 + dloc) * 3 + cls;
    int s = offsets[key], e = offsets[key + 1];
    int j = s;
    for (; j + 1 < e; j += 2) {
      unsigned int p0 = packed[j], p1 = packed[j + 1];
      int s0 = p0 & 0xFFFFF, t0 = p0 >> 20;
      int s1 = p1 & 0xFFFFF, t1 = p1 >> 20;
      uint4 h0 = *(const uint4*)&xb[(size_t)s0 * 64 + l16 * 4];
      uint4 r0 = *(const uint4*)&rb[(size_t)t0 * 64 + l16 * 4];
      uint4 h1 = *(const uint4*)&xb[(size_t)s1 * 64 + l16 * 4];
      uint4 r1 = *(const uint4*)&rb[(size_t)t1 * 64 + l16 * 4];
      acc8(a0, h0, r0);
      acc8(a1, h1, r1);
    }
    if (j < e) {
      unsigned int p0 = packed[j];
      int s0 = p0 & 0xFFFFF, t0 = p0 >> 20;
      uint4 h0 = *(const uint4*)&xb[(size_t)s0 * 64 + l16 * 4];
      uint4 r0 = *(const uint4*)&rb[(size_t)t0 * 64 + l16 * 4];
      acc8(a0, h0, r0);
    }
    uint4 o;
    o.x = pack2bf(a0[0] + a1[0], a0[1] + a1[1]);
    o.y = pack2bf(a0[2] + a1[2], a0[3] + a1[3]);
    o.z = pack2bf(a0[4] + a1[4], a0[5] + a1[5]);
    o.w = pack2bf(a0[6] + a1[6], a0[7] + a1[7]);
    *(uint4*)&As[dloc][cls * 128 + l16 * 8] = o;
  }
}

// ================= cooperative MEGA kernel =================
// grid = 1024 blocks (4/CU guaranteed: 27.6KB LDS, launch_bounds(256,4));
// each block owns tiles {bid, bid+1024, bid+2048, bid+3072}.  Per layer:
// gather+GEMM all tiles (acc in regs, stats->LDS->replica), grid.sync,
// collapse replicas, norm+tanh from REGISTERS -> xb (no C round-trip),
// grid.sync.  Then scoring in-kernel.  Replaces 7 dispatches.
struct MegaArgs {
  const unsigned int* entbf;
  const unsigned int* rfb;
  const unsigned int* r1b;
  const int* offsets;
  const unsigned int* packed;
  const unsigned short* WT1;
  const unsigned short* WT2;
  float* rep1;
  float* rep2;
  const float* g1; const float* b1;
  const float* g2; const float* b2;
  unsigned short* xb1;
  unsigned short* xb2;
  const float* r2;
  const int* triples;
  float* out;
  int nTiles; int nT; float invN;
};

static __device__ __forceinline__ void layer_pass(
    const MegaArgs& A,
    const unsigned int* __restrict__ xbin, const unsigned int* __restrict__ rbin,
    const unsigned short* __restrict__ WT, float* __restrict__ rep,
    const float* __restrict__ gamma, const float* __restrict__ beta,
    unsigned short* __restrict__ xbout,
    unsigned short (*As)[392], float* sSum, float* sSq,
    float* sc_s, float* bi_s, cg::grid_group& grid) {
  const int tid = threadIdx.x;
  const int wave = tid >> 6, lane = tid & 63;
  const int quad = lane >> 4, l16 = lane & 15;
  const int qid = (wave << 2) | quad;
  const f32x4 vz = {0.f, 0.f, 0.f, 0.f};
  f32x4 acc[4][2][2];
#pragma unroll
  for (int t = 0; t < 4; ++t)
#pragma unroll
    for (int a = 0; a < 2; ++a)
#pragma unroll
      for (int b = 0; b < 2; ++b) acc[t][a][b] = vz;

  if (tid < 128) { sSum[tid] = 0.f; sSq[tid] = 0.f; }
  __syncthreads();

  const unsigned short* Wp = WT + (size_t)(wave * 32 + l16) * 384 + quad * 8;

#pragma unroll
  for (int t = 0; t < 4; ++t) {
    int tile = blockIdx.x + t * 1024;
    bool valid = tile < A.nTiles;
    if (valid) gather96(xbin, rbin, A.offsets, A.packed, As, tile * 32, qid, l16);
    __syncthreads();
    if (valid) {
      short8 bc0 = *(const short8*)(Wp);
      short8 bc1 = *(const short8*)(Wp + 16 * 384);
#pragma unroll 1
      for (int it = 0; it < 12; ++it) {
        short8 bn0, bn1;
        if (it < 11) {
          bn0 = *(const short8*)(Wp + (it + 1) * 32);
          bn1 = *(const short8*)(Wp + 16 * 384 + (it + 1) * 32);
        }
        short8 a0 = *(const short8*)&As[l16][it * 32 + quad * 8];
        short8 a1 = *(const short8*)&As[16 + l16][it * 32 + quad * 8];
        acc[t][0][0] = __builtin_amdgcn_mfma_f32_16x16x32_bf16(a0, bc0, acc[t][0][0], 0, 0, 0);
        acc[t][0][1] = __builtin_amdgcn_mfma_f32_16x16x32_bf16(a0, bc1, acc[t][0][1], 0, 0, 0);
        acc[t][1][0] = __builtin_amdgcn_mfma_f32_16x16x32_bf16(a1, bc0, acc[t][1][0], 0, 0, 0);
        acc[t][1][1] = __builtin_amdgcn_mfma_f32_16x16x32_bf16(a1, bc1, acc[t][1][1], 0, 0, 0);
        if (it < 11) { bc0 = bn0; bc1 = bn1; }
      }
      float ps[2] = {}, pq[2] = {};
#pragma unroll
      for (int tr = 0; tr < 2; ++tr)
#pragma unroll
        for (int reg = 0; reg < 4; ++reg)
#pragma unroll
          for (int ct = 0; ct < 2; ++ct) {
            float v = acc[t][tr][ct][reg];
            ps[ct] += v; pq[ct] += v * v;
          }
#pragma unroll
      for (int ct = 0; ct < 2; ++ct) {
        int col = wave * 32 + ct * 16 + l16;
        atomicAdd(&sSum[col], ps[ct]);
        atomicAdd(&sSq[col], pq[ct]);
      }
    }
    __syncthreads();
  }
  if (tid < 128) {
    float* rp = rep + ((blockIdx.x & 31) << 8);
    atomicAdd(&rp[tid], sSum[tid]);
    atomicAdd(&rp[128 + tid], sSq[tid]);
  }
  grid.sync();

  if (tid < 128) {
    float s = 0.f, q = 0.f;
#pragma unroll
    for (int r = 0; r < 32; ++r) { s += rep[r * 256 + tid]; q += rep[r * 256 + 128 + tid]; }
    float mean = s * A.invN;
    float var = fmaxf(q * A.invN - mean * mean, 0.f);
    float sc = rsqrtf(var + 1e-5f) * gamma[tid];
    sc_s[tid] = sc;
    bi_s[tid] = beta[tid] - mean * sc;
  }
  __syncthreads();

#pragma unroll
  for (int t = 0; t < 4; ++t) {
    int tile = blockIdx.x + t * 1024;
    if (tile < A.nTiles) {
      int m0 = tile * 32;
#pragma unroll
      for (int tr = 0; tr < 2; ++tr)
#pragma unroll
        for (int reg = 0; reg < 4; ++reg) {
          int m = m0 + tr * 16 + quad * 4 + reg;
#pragma unroll
          for (int ct = 0; ct < 2; ++ct) {
            int col = wave * 32 + ct * 16 + l16;
            float f = tanhf(fmaf(acc[t][tr][ct][reg], sc_s[col], bi_s[col]));
            xbout[(size_t)m * 128 + col] = f2bf(f);
          }
        }
    }
  }
  grid.sync();
}

__global__ __launch_bounds__(256, 4) void k_mega(MegaArgs A) {
  __shared__ unsigned short As[32][392];
  __shared__ float sSum[128], sSq[128], sc_s[128], bi_s[128];
  cg::grid_group grid = cg::this_grid();

  layer_pass(A, A.entbf, A.rfb, A.WT1, A.rep1, A.g1, A.b1, A.xb1,
             As, sSum, sSq, sc_s, bi_s, grid);
  layer_pass(A, (const unsigned int*)A.xb1, A.r1b, A.WT2, A.rep2, A.g2, A.b2, A.xb2,
             As, sSum, sSq, sc_s, bi_s, grid);

  // ---- scoring: 1024 blocks x 4 waves = 4096 waves, one per triple ----
  int gw = blockIdx.x * 4 + (threadIdx.x >> 6);
  if (gw < A.nT) {
    int lane = threadIdx.x & 63;
    const unsigned int* xbu = (const unsigned int*)A.xb2;
    int h = A.triples[gw * 3], rel = A.triples[gw * 3 + 1], tl = A.triples[gw * 3 + 2];
    float2 a = bf2f(xbu[(size_t)h * 64 + lane]);
    float2 b = *(const float2*)&A.r2[(size_t)rel * 128 + lane * 2];
    float2 c = bf2f(xbu[(size_t)tl * 64 + lane]);
    float s = fabsf(a.x + b.x - c.x) + fabsf(a.y + b.y - c.y);
#pragma unroll
    for (int off = 32; off > 0; off >>= 1) s += __shfl_down(s, off);
    if (lane == 0) A.out[gw] = s;
  }
}

// ================= fallback path (verified R5 kernels) =================
__global__ __launch_bounds__(256, 6) void k_fused(
    const unsigned int* __restrict__ xb, const unsigned int* __restrict__ rb,
    const int* __restrict__ offsets, const unsigned int* __restrict__ packed,
    const unsigned short* __restrict__ WT, unsigned short* __restrict__ C,
    float* __restrict__ statsRep, int M) {
  __shared__ unsigned short As[32][392];
  __shared__ float sSum[128], sSq[128];
  const int tid = threadIdx.x;
  const int m0 = blockIdx.x * 32;
  const int wave = tid >> 6, lane = tid & 63;
  const int quad = lane >> 4, l16 = lane & 15;
  const int qid = (wave << 2) | quad;
  if (tid < 128) { sSum[tid] = 0.f; sSq[tid] = 0.f; }
  gather96(xb, rb, offsets, packed, As, m0, qid, l16);
  __syncthreads();
  const unsigned short* Wp = WT + (size_t)(wave * 32 + l16) * 384 + quad * 8;
  short8 bc0 = *(const short8*)(Wp);
  short8 bc1 = *(const short8*)(Wp + 16 * 384);
  f32x4 acc[2][2] = {};
#pragma unroll 1
  for (int it = 0; it < 12; ++it) {
    short8 bn0, bn1;
    if (it < 11) {
      bn0 = *(const short8*)(Wp + (it + 1) * 32);
      bn1 = *(const short8*)(Wp + 16 * 384 + (it + 1) * 32);
    }
    short8 a0 = *(const short8*)&As[l16][it * 32 + quad * 8];
    short8 a1 = *(const short8*)&As[16 + l16][it * 32 + quad * 8];
    acc[0][0] = __builtin_amdgcn_mfma_f32_16x16x32_bf16(a0, bc0, acc[0][0], 0, 0, 0);
    acc[0][1] = __builtin_amdgcn_mfma_f32_16x16x32_bf16(a0, bc1, acc[0][1], 0, 0, 0);
    acc[1][0] = __builtin_amdgcn_mfma_f32_16x16x32_bf16(a1, bc0, acc[1][0], 0, 0, 0);
    acc[1][1] = __builtin_amdgcn_mfma_f32_16x16x32_bf16(a1, bc1, acc[1][1], 0, 0, 0);
    if (it < 11) { bc0 = bn0; bc1 = bn1; }
  }
  float ps[2] = {}, pq[2] = {};
#pragma unroll
  for (int t = 0; t < 2; ++t)
#pragma unroll
    for (int reg = 0; reg < 4; ++reg) {
      int m = m0 + t * 16 + quad * 4 + reg;
      if (m < M) {
#pragma unroll
        for (int ct = 0; ct < 2; ++ct) {
          float v = acc[t][ct][reg];
          int col = wave * 32 + ct * 16 + l16;
          C[(size_t)m * 128 + col] = f2bf(v);
          ps[ct] += v; pq[ct] += v * v;
        }
      }
    }
#pragma unroll
  for (int ct = 0; ct < 2; ++ct) {
    int col = wave * 32 + ct * 16 + l16;
    atomicAdd(&sSum[col], ps[ct]);
    atomicAdd(&sSq[col], pq[ct]);
  }
  __syncthreads();
  if (tid < 128) {
    float* rep = statsRep + ((blockIdx.x & 31) << 8);
    atomicAdd(&rep[tid], sSum[tid]);
    atomicAdd(&rep[128 + tid], sSq[tid]);
  }
}

__global__ void k_collapse(const float* __restrict__ rep, float* __restrict__ fin) {
  int c = threadIdx.x;
  float s = 0.f;
#pragma unroll
  for (int r = 0; r < 32; ++r) s += rep[r * 256 + c];
  fin[c] = s;
}

__global__ void k_norm(const uint4* __restrict__ Cb4,
                       const float* __restrict__ sums, const float* __restrict__ sumsq,
                       const float* __restrict__ gamma, const float* __restrict__ beta,
                       float invN, uint4* __restrict__ xb4, int nQuad) {
  __shared__ float sc_s[128], bi_s[128];
  if (threadIdx.x < 128) {
    int c = threadIdx.x;
    float mean = sums[c] * invN;
    float var = fmaxf(sumsq[c] * invN - mean * mean, 0.f);
    float sc = rsqrtf(var + 1e-5f) * gamma[c];
    sc_s[c] = sc;
    bi_s[c] = beta[c] - mean * sc;
  }
  __syncthreads();
  int i = blockIdx.x * blockDim.x + threadIdx.x;
  if (i >= nQuad) return;
  uint4 v = Cb4[i];
  int j = (i * 4) & 63;
  uint4 o;
  float2 f;
  f = bf2f(v.x);
  o.x = pack2bf(tanhf(fmaf(f.x, sc_s[2*j],   bi_s[2*j])),   tanhf(fmaf(f.y, sc_s[2*j+1], bi_s[2*j+1])));
  f = bf2f(v.y);
  o.y = pack2bf(tanhf(fmaf(f.x, sc_s[2*j+2], bi_s[2*j+2])), tanhf(fmaf(f.y, sc_s[2*j+3], bi_s[2*j+3])));
  f = bf2f(v.z);
  o.z = pack2bf(tanhf(fmaf(f.x, sc_s[2*j+4], bi_s[2*j+4])), tanhf(fmaf(f.y, sc_s[2*j+5], bi_s[2*j+5])));
  f = bf2f(v.w);
  o.w = pack2bf(tanhf(fmaf(f.x, sc_s[2*j+6], bi_s[2*j+6])), tanhf(fmaf(f.y, sc_s[2*j+7], bi_s[2*j+7])));
  xb4[i] = o;
}

__global__ void k_score(const unsigned int* __restrict__ xb, const float* __restrict__ r,
                        const int* __restrict__ triples, float* __restrict__ out, int nT) {
  int gid = blockIdx.x * blockDim.x + threadIdx.x;
  int t = gid >> 6;
  if (t >= nT) return;
  int lane = gid & 63;
  int h = triples[t * 3], rel = triples[t * 3 + 1], tl = triples[t * 3 + 2];
  float2 a = bf2f(xb[(size_t)h * 64 + lane]);
  float2 b = *(const float2*)&r[(size_t)rel * 128 + lane * 2];
  float2 cc = bf2f(xb[(size_t)tl * 64 + lane]);
  float s = fabsf(a.x + b.x - cc.x) + fabsf(a.y + b.y - cc.y);
#pragma unroll
  for (int off = 32; off > 0; off >>= 1) s += __shfl_down(s, off);
  if (lane == 0) out[t] = s;
}

extern "C" void kernel_launch(void* const* d_in, const int* in_sizes, int n_in,
                              void* d_out, int out_size, void* d_ws, size_t ws_size,
                              hipStream_t stream) {
  const float* ent   = (const float*)d_in[0];
  const float* bases = (const float*)d_in[1];
  const float* coeff = (const float*)d_in[2];
  const float* selfr = (const float*)d_in[3];
  const float* W1    = (const float*)d_in[4];
  const float* relw1 = (const float*)d_in[5];
  const float* g1    = (const float*)d_in[6];
  const float* b1    = (const float*)d_in[7];
  const float* W2    = (const float*)d_in[8];
  const float* relw2 = (const float*)d_in[9];
  const float* g2    = (const float*)d_in[10];
  const float* b2    = (const float*)d_in[11];
  const int* ent_ids = (const int*)d_in[12];
  const int* ei      = (const int*)d_in[13];
  const int* et      = (const int*)d_in[14];
  const int* yk      = (const int*)d_in[15];
  const int* triples = (const int*)d_in[16];

  const int M  = in_sizes[0] / 128;   // 100000
  const int nE = in_sizes[14];        // 800000
  const int nT = in_sizes[16] / 3;    // 4096
  const int nKeys = M * 3;
  const int nScanBlocks = (nKeys + 1023) / 1024;
  const int rsz = (nKeys + 7) / 8;

  // workspace layout (~140 MB)
  float* p = (float*)d_ws;
  float* r2    = p; p += 401 * 128;
  float* statsAll = p; p += 16896;     // rep1(32x256) | rep2(32x256) | fin1 | fin2
  float* rep1 = statsAll;
  float* rep2 = statsAll + 32 * 256;
  float* fin1 = statsAll + 64 * 256;
  float* fin2 = fin1 + 256;
  unsigned short* Cb  = (unsigned short*)p;                       // fallback only
  unsigned short* xb1 = Cb + (size_t)M * 128;
  unsigned short* xb2 = xb1 + (size_t)M * 128;
  unsigned int* entbf = (unsigned int*)(xb2 + (size_t)M * 128);   // M*64
  unsigned int* rfb   = entbf + (size_t)M * 64;                   // 401*64
  unsigned int* r1b   = rfb + 401 * 64;
  unsigned short* WT1 = (unsigned short*)(r1b + 401 * 64);
  unsigned short* WT2 = WT1 + 128 * 384;
  int* counts  = (int*)(WT2 + 128 * 384);
  int* offsets = counts + nKeys;
  int* cursor  = offsets + nKeys + 1;
  int* slocal  = cursor + nKeys;
  int* sblock  = slocal + nKeys;
  int* scarry  = sblock + nScanBlocks;
  unsigned int* bucket = (unsigned int*)(scarry + nScanBlocks);

  float* out = (float*)d_out;

  const int nPairs = M * 64;
  const int nQuad  = M * 16;
  const int cvtB = (nPairs + 255) / 256;
  const int cntB = (nKeys + 255) / 256;
  const int zeroB = 66;
  const int prepBlocks = 585 + cvtB + cntB + zeroB;
  const int nTiles = (M + 31) / 32;
  const dim3 rangedGrid(8, (nE + 1023) / 1024);

  k_prep<<<prepBlocks, 256, 0, stream>>>(coeff, bases, selfr, relw1, relw2,
                                         rfb, r1b, r2, W1, W2, WT1, WT2,
                                         ent, ent_ids, entbf, counts, statsAll,
                                         nPairs, nKeys, cvtB, cntB);

  k_histR<<<rangedGrid, 256, 0, stream>>>(ei, yk, counts, nE, rsz);
  k_scan1<<<nScanBlocks, 1024, 0, stream>>>(counts, slocal, sblock, nKeys);
  k_scan2<<<1, 1024, 0, stream>>>(sblock, scarry, offsets, nKeys, nScanBlocks);
  k_scan3<<<nScanBlocks, 1024, 0, stream>>>(slocal, scarry, offsets, cursor, nKeys);
  k_fillR<<<rangedGrid, 256, 0, stream>>>(ei, et, yk, cursor, bucket, nE, rsz);

  MegaArgs margs;
  margs.entbf = entbf; margs.rfb = rfb; margs.r1b = r1b;
  margs.offsets = offsets; margs.packed = bucket;
  margs.WT1 = WT1; margs.WT2 = WT2;
  margs.rep1 = rep1; margs.rep2 = rep2;
  margs.g1 = g1; margs.b1 = b1; margs.g2 = g2; margs.b2 = b2;
  margs.xb1 = xb1; margs.xb2 = xb2;
  margs.r2 = r2; margs.triples = triples; margs.out = out;
  margs.nTiles = nTiles; margs.nT = nT; margs.invN = 1.0f / M;
  void* kargs[] = {(void*)&margs};
  hipError_t merr = hipLaunchCooperativeKernel((const void*)k_mega, dim3(1024), dim3(256),
                                               kargs, 0, stream);
  if (merr != hipSuccess) {
    // fallback: verified R5 pipeline
    const int fusedBlocks = nTiles;
    const int normBlocks = (nQuad + 255) / 256;
    k_fused<<<fusedBlocks, 256, 0, stream>>>(entbf, rfb, offsets, bucket, WT1, Cb, rep1, M);
    k_collapse<<<1, 256, 0, stream>>>(rep1, fin1);
    k_norm<<<normBlocks, 256, 0, stream>>>((const uint4*)Cb, fin1, fin1 + 128, g1, b1,
                                           1.0f / M, (uint4*)xb1, nQuad);
    k_fused<<<fusedBlocks, 256, 0, stream>>>((const unsigned int*)xb1, r1b, offsets, bucket,
                                             WT2, Cb, rep2, M);
    k_collapse<<<1, 256, 0, stream>>>(rep2, fin2);
    k_norm<<<normBlocks, 256, 0, stream>>>((const uint4*)Cb, fin2, fin2 + 128, g2, b2,
                                           1.0f / M, (uint4*)xb2, nQuad);
    k_score<<<(nT * 64 + 255) / 256, 256, 0, stream>>>((const unsigned int*)xb2, r2,
                                                       triples, out, nT);
  }
}

// Round 8
// 453.939 us; speedup vs baseline: 2.1905x; 2.1905x over previous
//
#include <hip/hip_runtime.h>
#include <cstdint>

typedef __attribute__((ext_vector_type(8))) short short8;
typedef __attribute__((ext_vector_type(4))) float f32x4;

static __device__ __forceinline__ unsigned short f2bf(float f) {
  unsigned int u = __float_as_uint(f);
  unsigned int r = (u + 0x7FFFu + ((u >> 16) & 1u)) >> 16;   // RNE
  return (unsigned short)r;
}
static __device__ __forceinline__ unsigned int pack2bf(float a, float b) {
  return (unsigned int)f2bf(a) | ((unsigned int)f2bf(b) << 16);
}
static __device__ __forceinline__ float2 bf2f(unsigned int u) {
  return make_float2(__uint_as_float(u << 16), __uint_as_float(u & 0xFFFF0000u));
}
static __device__ __forceinline__ void acc8(float* a, uint4 h, uint4 r) {
  float2 f, g;
  f = bf2f(h.x); g = bf2f(r.x); a[0] += f.x - g.x; a[1] += f.y - g.y;
  f = bf2f(h.y); g = bf2f(r.y); a[2] += f.x - g.x; a[3] += f.y - g.y;
  f = bf2f(h.z); g = bf2f(r.z); a[4] += f.x - g.x; a[5] += f.y - g.y;
  f = bf2f(h.w); g = bf2f(r.w); a[6] += f.x - g.x; a[7] += f.y - g.y;
}

// ---- one-shot prep kernel (R5-verified) ----
__global__ __launch_bounds__(256) void k_prep(
    const float* __restrict__ coeff, const float* __restrict__ bases,
    const float* __restrict__ selfr, const float* __restrict__ relw1,
    const float* __restrict__ relw2,
    unsigned int* __restrict__ rfb, unsigned int* __restrict__ r1b,
    float* __restrict__ r2,
    const float* __restrict__ W1, const float* __restrict__ W2,
    unsigned short* __restrict__ WT1, unsigned short* __restrict__ WT2,
    const float* __restrict__ ent, const int* __restrict__ ent_ids,
    unsigned int* __restrict__ entbf,
    int* __restrict__ counts, float* __restrict__ stats,
    int nPairs, int nKeys, int cvtB, int cntB) {
  int b = blockIdx.x, tid = threadIdx.x;
  if (b < 201) {
    __shared__ float row[2][128], r1row[2][128];
    int half = tid >> 7, c = tid & 127;
    int r = 2 * b + half;
    bool ok = (r <= 400);
    if (ok) {
      float v;
      if (r == 400) {
        v = selfr[c];
      } else {
        int rr = (r < 200) ? r : r - 200;
        float s = 0.f;
#pragma unroll 10
        for (int k = 0; k < 50; ++k) s += coeff[rr * 50 + k] * bases[k * 128 + c];
        v = (r < 200) ? s : -s;
      }
      row[half][c] = v;
    }
    __syncthreads();
    if (ok && c < 64) rfb[r * 64 + c] = pack2bf(row[half][2 * c], row[half][2 * c + 1]);
    if (ok) {
      float s = 0.f;
#pragma unroll 8
      for (int k = 0; k < 128; ++k) s += row[half][k] * relw1[k * 128 + c];
      r1row[half][c] = s;
    }
    __syncthreads();
    if (ok && c < 64) r1b[r * 64 + c] = pack2bf(r1row[half][2 * c], r1row[half][2 * c + 1]);
    if (ok) {
      float s = 0.f;
#pragma unroll 8
      for (int k = 0; k < 128; ++k) s += r1row[half][k] * relw2[k * 128 + c];
      r2[r * 128 + c] = s;
    }
  } else if (b < 585) {
    int idx = (b - 201) * 256 + tid;
    const int half = 128 * 384;
    const float* W = (idx < half) ? W1 : W2;
    unsigned short* WT = (idx < half) ? WT1 : WT2;
    int id2 = (idx < half) ? idx : idx - half;
    int n = id2 & 127, k = id2 >> 7;
    int kk = k >> 7, kr = k & 127;
    WT[(size_t)n * 384 + k] = f2bf(W[(size_t)kk * 16384 + kr * 128 + n]);
  } else if (b < 585 + cvtB) {
    int i = (b - 585) * 256 + tid;
    if (i < nPairs) {
      int e = i >> 6;
      int src = ent_ids[e];
      float2 v = *(const float2*)&ent[(size_t)src * 128 + (i & 63) * 2];
      entbf[i] = pack2bf(v.x, v.y);
    }
  } else if (b < 585 + cvtB + cntB) {
    int i = (b - (585 + cvtB)) * 256 + tid;
    if (i < nKeys) counts[i] = 0;
  } else {
    int i = (b - (585 + cvtB + cntB)) * 256 + tid;
    if (i < 16896) stats[i] = 0.f;
  }
}

// ---- CSR build (unchanged, range-partitioned) ----
__global__ __launch_bounds__(256) void k_histR(const int* __restrict__ ei, const int* __restrict__ y,
                                               int* __restrict__ counts, int nE, int rsz) {
  int r = blockIdx.x;
  int e0 = blockIdx.y * 1024;
#pragma unroll
  for (int i = 0; i < 4; ++i) {
    int e = e0 + i * 256 + threadIdx.x;
    if (e < nE) {
      int key = ei[nE + e] * 3 + y[e];
      if (key / rsz == r) atomicAdd(&counts[key], 1);
    }
  }
}

__global__ void k_scan1(const int* __restrict__ counts, int* __restrict__ local,
                        int* __restrict__ blockSums, int n) {
  __shared__ int sdata[1024];
  int tid = threadIdx.x;
  int i = blockIdx.x * 1024 + tid;
  int v = (i < n) ? counts[i] : 0;
  sdata[tid] = v;
  __syncthreads();
  for (int off = 1; off < 1024; off <<= 1) {
    int t = (tid >= off) ? sdata[tid - off] : 0;
    __syncthreads();
    sdata[tid] += t;
    __syncthreads();
  }
  if (i < n) local[i] = sdata[tid] - v;
  if (tid == 1023) blockSums[blockIdx.x] = sdata[1023];
}

__global__ void k_scan2(const int* __restrict__ blockSums, int* __restrict__ carries,
                        int* __restrict__ offsets, int n, int nb) {
  __shared__ int sdata[1024];
  int tid = threadIdx.x;
  int v = (tid < nb) ? blockSums[tid] : 0;
  sdata[tid] = v;
  __syncthreads();
  for (int off = 1; off < 1024; off <<= 1) {
    int t = (tid >= off) ? sdata[tid - off] : 0;
    __syncthreads();
    sdata[tid] += t;
    __syncthreads();
  }
  if (tid < nb) carries[tid] = sdata[tid] - v;
  if (tid == 1023) offsets[n] = sdata[1023];
}

__global__ void k_scan3(const int* __restrict__ local, const int* __restrict__ carries,
                        int* __restrict__ offsets, int* __restrict__ cursor, int n) {
  int i = blockIdx.x * 1024 + threadIdx.x;
  if (i >= n) return;
  int v = local[i] + carries[blockIdx.x];
  offsets[i] = v;
  cursor[i] = v;
}

__global__ __launch_bounds__(256) void k_fillR(const int* __restrict__ ei, const int* __restrict__ et,
                                               const int* __restrict__ y, int* __restrict__ cursor,
                                               unsigned int* __restrict__ bucket, int nE, int rsz) {
  int r = blockIdx.x;
  int e0 = blockIdx.y * 1024;
#pragma unroll
  for (int i = 0; i < 4; ++i) {
    int e = e0 + i * 256 + threadIdx.x;
    if (e < nE) {
      int key = ei[nE + e] * 3 + y[e];
      if (key / rsz == r) {
        int slot = atomicAdd(&cursor[key], 1);
        bucket[slot] = (unsigned int)ei[e] | ((unsigned int)et[e] << 20);
      }
    }
  }
}

// 2-edge-unroll tail for a single segment (same accumulation order as R5)
static __device__ __forceinline__ void seg_tail(
    const unsigned int* __restrict__ xb, const unsigned int* __restrict__ rb,
    const unsigned int* __restrict__ packed, int j, int e, int l16,
    float* a0, float* a1) {
  for (; j + 1 < e; j += 2) {
    unsigned int p0 = packed[j], p1 = packed[j + 1];
    int s0 = p0 & 0xFFFFF, t0 = p0 >> 20;
    int s1 = p1 & 0xFFFFF, t1 = p1 >> 20;
    uint4 h0 = *(const uint4*)&xb[(size_t)s0 * 64 + l16 * 4];
    uint4 r0 = *(const uint4*)&rb[(size_t)t0 * 64 + l16 * 4];
    uint4 h1 = *(const uint4*)&xb[(size_t)s1 * 64 + l16 * 4];
    uint4 r1 = *(const uint4*)&rb[(size_t)t1 * 64 + l16 * 4];
    acc8(a0, h0, r0);
    acc8(a1, h1, r1);
  }
  if (j < e) {
    unsigned int p0 = packed[j];
    int s0 = p0 & 0xFFFFF, t0 = p0 >> 20;
    uint4 h0 = *(const uint4*)&xb[(size_t)s0 * 64 + l16 * 4];
    uint4 r0 = *(const uint4*)&rb[(size_t)t0 * 64 + l16 * 4];
    acc8(a0, h0, r0);
  }
}

// ---- FUSED gather-aggregate + GEMM + BN-stats, BM=32 (R5 structure).
// R7 change: dual-row gather.  Each quad-group owns rows 2qid, 2qid+1; the
// 7 segment offsets are contiguous and loaded upfront; the inner loop walks
// BOTH rows' class-segments concurrently (8 loads in flight vs 4) to double
// MLP in the latency-bound gather.  Per-row FP accumulation order unchanged.
__global__ __launch_bounds__(256, 4) void k_fused(
    const unsigned int* __restrict__ xb, const unsigned int* __restrict__ rb,
    const int* __restrict__ offsets, const unsigned int* __restrict__ packed,
    const unsigned short* __restrict__ WT, unsigned short* __restrict__ C,
    float* __restrict__ statsRep, int M) {
  __shared__ unsigned short As[32][392];
  __shared__ float sSum[128], sSq[128];
  const int tid = threadIdx.x;
  const int m0 = blockIdx.x * 32;
  const int wave = tid >> 6, lane = tid & 63;
  const int quad = lane >> 4, l16 = lane & 15;
  const int qid = (wave << 2) | quad;          // 0..15: rows 2qid, 2qid+1
  if (tid < 128) { sSum[tid] = 0.f; sSq[tid] = 0.f; }

  // ---- gather phase: dual-row, 3 classes ----
  {
    const int dst0 = m0 + 2 * qid;
    const int dst1 = dst0 + 1;
    int off[7];
#pragma unroll
    for (int i = 0; i < 7; ++i) off[i] = 0;
    if (dst1 < M) {
      int base = dst0 * 3;
#pragma unroll
      for (int i = 0; i < 7; ++i) off[i] = offsets[base + i];
    } else if (dst0 < M) {
      int base = dst0 * 3;
#pragma unroll
      for (int i = 0; i < 4; ++i) off[i] = offsets[base + i];
      off[4] = off[3]; off[5] = off[3]; off[6] = off[3];
    }
#pragma unroll 1
    for (int cls = 0; cls < 3; ++cls) {
      int j0 = off[cls],     e0 = off[cls + 1];
      int j1 = off[cls + 3], e1 = off[cls + 4];
      float a0[8] = {}, a1[8] = {}, b0[8] = {}, b1[8] = {};
      // dual-cursor main loop: 8 loads in flight
      while (j0 + 1 < e0 && j1 + 1 < e1) {
        unsigned int p00 = packed[j0], p01 = packed[j0 + 1];
        unsigned int p10 = packed[j1], p11 = packed[j1 + 1];
        int s00 = p00 & 0xFFFFF, t00 = p00 >> 20;
        int s01 = p01 & 0xFFFFF, t01 = p01 >> 20;
        int s10 = p10 & 0xFFFFF, t10 = p10 >> 20;
        int s11 = p11 & 0xFFFFF, t11 = p11 >> 20;
        uint4 h00 = *(const uint4*)&xb[(size_t)s00 * 64 + l16 * 4];
        uint4 r00 = *(const uint4*)&rb[(size_t)t00 * 64 + l16 * 4];
        uint4 h01 = *(const uint4*)&xb[(size_t)s01 * 64 + l16 * 4];
        uint4 r01 = *(const uint4*)&rb[(size_t)t01 * 64 + l16 * 4];
        uint4 h10 = *(const uint4*)&xb[(size_t)s10 * 64 + l16 * 4];
        uint4 r10 = *(const uint4*)&rb[(size_t)t10 * 64 + l16 * 4];
        uint4 h11 = *(const uint4*)&xb[(size_t)s11 * 64 + l16 * 4];
        uint4 r11 = *(const uint4*)&rb[(size_t)t11 * 64 + l16 * 4];
        acc8(a0, h00, r00);
        acc8(a1, h01, r01);
        acc8(b0, h10, r10);
        acc8(b1, h11, r11);
        j0 += 2; j1 += 2;
      }
      seg_tail(xb, rb, packed, j0, e0, l16, a0, a1);
      seg_tail(xb, rb, packed, j1, e1, l16, b0, b1);
      uint4 o;
      o.x = pack2bf(a0[0] + a1[0], a0[1] + a1[1]);
      o.y = pack2bf(a0[2] + a1[2], a0[3] + a1[3]);
      o.z = pack2bf(a0[4] + a1[4], a0[5] + a1[5]);
      o.w = pack2bf(a0[6] + a1[6], a0[7] + a1[7]);
      *(uint4*)&As[2 * qid][cls * 128 + l16 * 8] = o;
      o.x = pack2bf(b0[0] + b1[0], b0[1] + b1[1]);
      o.y = pack2bf(b0[2] + b1[2], b0[3] + b1[3]);
      o.z = pack2bf(b0[4] + b1[4], b0[5] + b1[5]);
      o.w = pack2bf(b0[6] + b1[6], b0[7] + b1[7]);
      *(uint4*)&As[2 * qid + 1][cls * 128 + l16 * 8] = o;
    }
  }
  __syncthreads();

  // ---- GEMM phase: C[32x128] = As[32x384] @ WT^T, B streamed from L2 ----
  const unsigned short* Wp = WT + (size_t)(wave * 32 + l16) * 384 + quad * 8;
  short8 bc0 = *(const short8*)(Wp);
  short8 bc1 = *(const short8*)(Wp + 16 * 384);
  f32x4 acc[2][2] = {};
#pragma unroll 1
  for (int it = 0; it < 12; ++it) {
    short8 bn0, bn1;
    if (it < 11) {
      bn0 = *(const short8*)(Wp + (it + 1) * 32);
      bn1 = *(const short8*)(Wp + 16 * 384 + (it + 1) * 32);
    }
    short8 a0 = *(const short8*)&As[l16][it * 32 + quad * 8];
    short8 a1 = *(const short8*)&As[16 + l16][it * 32 + quad * 8];
    acc[0][0] = __builtin_amdgcn_mfma_f32_16x16x32_bf16(a0, bc0, acc[0][0], 0, 0, 0);
    acc[0][1] = __builtin_amdgcn_mfma_f32_16x16x32_bf16(a0, bc1, acc[0][1], 0, 0, 0);
    acc[1][0] = __builtin_amdgcn_mfma_f32_16x16x32_bf16(a1, bc0, acc[1][0], 0, 0, 0);
    acc[1][1] = __builtin_amdgcn_mfma_f32_16x16x32_bf16(a1, bc1, acc[1][1], 0, 0, 0);
    if (it < 11) { bc0 = bn0; bc1 = bn1; }
  }

  // ---- epilogue: bf16 C store + BN stats (replicated atomics) ----
  float ps[2] = {}, pq[2] = {};
#pragma unroll
  for (int t = 0; t < 2; ++t)
#pragma unroll
    for (int reg = 0; reg < 4; ++reg) {
      int m = m0 + t * 16 + quad * 4 + reg;
      if (m < M) {
#pragma unroll
        for (int ct = 0; ct < 2; ++ct) {
          float v = acc[t][ct][reg];
          int col = wave * 32 + ct * 16 + l16;
          C[(size_t)m * 128 + col] = f2bf(v);
          ps[ct] += v; pq[ct] += v * v;
        }
      }
    }
#pragma unroll
  for (int ct = 0; ct < 2; ++ct) {
    int col = wave * 32 + ct * 16 + l16;
    atomicAdd(&sSum[col], ps[ct]);
    atomicAdd(&sSq[col], pq[ct]);
  }
  __syncthreads();
  if (tid < 128) {
    float* rep = statsRep + ((blockIdx.x & 31) << 8);
    atomicAdd(&rep[tid], sSum[tid]);
    atomicAdd(&rep[128 + tid], sSq[tid]);
  }
}

// fold 32 stat replicas -> final 256 floats (sums|sumsq)
__global__ void k_collapse(const float* __restrict__ rep, float* __restrict__ fin) {
  int c = threadIdx.x;
  float s = 0.f;
#pragma unroll
  for (int r = 0; r < 32; ++r) s += rep[r * 256 + c];
  fin[c] = s;
}

// norm + tanh, uint4-vectorized (4 bf16-pairs per thread)
__global__ void k_norm(const uint4* __restrict__ Cb4,
                       const float* __restrict__ sums, const float* __restrict__ sumsq,
                       const float* __restrict__ gamma, const float* __restrict__ beta,
                       float invN, uint4* __restrict__ xb4, int nQuad) {
  __shared__ float sc_s[128], bi_s[128];
  if (threadIdx.x < 128) {
    int c = threadIdx.x;
    float mean = sums[c] * invN;
    float var = fmaxf(sumsq[c] * invN - mean * mean, 0.f);
    float sc = rsqrtf(var + 1e-5f) * gamma[c];
    sc_s[c] = sc;
    bi_s[c] = beta[c] - mean * sc;
  }
  __syncthreads();
  int i = blockIdx.x * blockDim.x + threadIdx.x;
  if (i >= nQuad) return;
  uint4 v = Cb4[i];
  int j = (i * 4) & 63;
  uint4 o;
  float2 f;
  f = bf2f(v.x);
  o.x = pack2bf(tanhf(fmaf(f.x, sc_s[2*j],   bi_s[2*j])),   tanhf(fmaf(f.y, sc_s[2*j+1], bi_s[2*j+1])));
  f = bf2f(v.y);
  o.y = pack2bf(tanhf(fmaf(f.x, sc_s[2*j+2], bi_s[2*j+2])), tanhf(fmaf(f.y, sc_s[2*j+3], bi_s[2*j+3])));
  f = bf2f(v.z);
  o.z = pack2bf(tanhf(fmaf(f.x, sc_s[2*j+4], bi_s[2*j+4])), tanhf(fmaf(f.y, sc_s[2*j+5], bi_s[2*j+5])));
  f = bf2f(v.w);
  o.w = pack2bf(tanhf(fmaf(f.x, sc_s[2*j+6], bi_s[2*j+6])), tanhf(fmaf(f.y, sc_s[2*j+7], bi_s[2*j+7])));
  xb4[i] = o;
}

// one wave per triple: sum_d |x[h]+r[rel]-x[t]|
__global__ void k_score(const unsigned int* __restrict__ xb, const float* __restrict__ r,
                        const int* __restrict__ triples, float* __restrict__ out, int nT) {
  int gid = blockIdx.x * blockDim.x + threadIdx.x;
  int t = gid >> 6;
  if (t >= nT) return;
  int lane = gid & 63;
  int h = triples[t * 3], rel = triples[t * 3 + 1], tl = triples[t * 3 + 2];
  float2 a = bf2f(xb[(size_t)h * 64 + lane]);
  float2 b = *(const float2*)&r[(size_t)rel * 128 + lane * 2];
  float2 cc = bf2f(xb[(size_t)tl * 64 + lane]);
  float s = fabsf(a.x + b.x - cc.x) + fabsf(a.y + b.y - cc.y);
#pragma unroll
  for (int off = 32; off > 0; off >>= 1) s += __shfl_down(s, off);
  if (lane == 0) out[t] = s;
}

extern "C" void kernel_launch(void* const* d_in, const int* in_sizes, int n_in,
                              void* d_out, int out_size, void* d_ws, size_t ws_size,
                              hipStream_t stream) {
  const float* ent   = (const float*)d_in[0];
  const float* bases = (const float*)d_in[1];
  const float* coeff = (const float*)d_in[2];
  const float* selfr = (const float*)d_in[3];
  const float* W1    = (const float*)d_in[4];
  const float* relw1 = (const float*)d_in[5];
  const float* g1    = (const float*)d_in[6];
  const float* b1    = (const float*)d_in[7];
  const float* W2    = (const float*)d_in[8];
  const float* relw2 = (const float*)d_in[9];
  const float* g2    = (const float*)d_in[10];
  const float* b2    = (const float*)d_in[11];
  const int* ent_ids = (const int*)d_in[12];
  const int* ei      = (const int*)d_in[13];
  const int* et      = (const int*)d_in[14];
  const int* yk      = (const int*)d_in[15];
  const int* triples = (const int*)d_in[16];

  const int M  = in_sizes[0] / 128;   // 100000
  const int nE = in_sizes[14];        // 800000
  const int nT = in_sizes[16] / 3;    // 4096
  const int nKeys = M * 3;
  const int nScanBlocks = (nKeys + 1023) / 1024;
  const int rsz = (nKeys + 7) / 8;

  // workspace layout (~88 MB)
  float* p = (float*)d_ws;
  float* r2    = p; p += 401 * 128;
  float* statsAll = p; p += 16896;     // rep1(32x256) | rep2(32x256) | fin1 | fin2
  float* rep1 = statsAll;
  float* rep2 = statsAll + 32 * 256;
  float* fin1 = statsAll + 64 * 256;
  float* fin2 = fin1 + 256;
  unsigned short* Cb  = (unsigned short*)p;                       // M*128 bf16
  unsigned int* entbf = (unsigned int*)(Cb + (size_t)M * 128);    // M*64
  unsigned int* xb    = entbf + (size_t)M * 64;                   // M*64
  unsigned int* rfb   = xb + (size_t)M * 64;                      // 401*64
  unsigned int* r1b   = rfb + 401 * 64;                           // 401*64
  unsigned short* WT1 = (unsigned short*)(r1b + 401 * 64);
  unsigned short* WT2 = WT1 + 128 * 384;
  int* counts  = (int*)(WT2 + 128 * 384);
  int* offsets = counts + nKeys;
  int* cursor  = offsets + nKeys + 1;
  int* slocal  = cursor + nKeys;
  int* sblock  = slocal + nKeys;
  int* scarry  = sblock + nScanBlocks;
  unsigned int* bucket = (unsigned int*)(scarry + nScanBlocks);

  float* out = (float*)d_out;

  const int nPairs = M * 64;
  const int nQuad  = M * 16;
  const int cvtB = (nPairs + 255) / 256;
  const int cntB = (nKeys + 255) / 256;
  const int zeroB = 66;
  const int prepBlocks = 585 + cvtB + cntB + zeroB;
  const int fusedBlocks = (M + 31) / 32;
  const int normBlocks = (nQuad + 255) / 256;
  const dim3 rangedGrid(8, (nE + 1023) / 1024);

  k_prep<<<prepBlocks, 256, 0, stream>>>(coeff, bases, selfr, relw1, relw2,
                                         rfb, r1b, r2, W1, W2, WT1, WT2,
                                         ent, ent_ids, entbf, counts, statsAll,
                                         nPairs, nKeys, cvtB, cntB);

  // CSR over (dst, class)
  k_histR<<<rangedGrid, 256, 0, stream>>>(ei, yk, counts, nE, rsz);
  k_scan1<<<nScanBlocks, 1024, 0, stream>>>(counts, slocal, sblock, nKeys);
  k_scan2<<<1, 1024, 0, stream>>>(sblock, scarry, offsets, nKeys, nScanBlocks);
  k_scan3<<<nScanBlocks, 1024, 0, stream>>>(slocal, scarry, offsets, cursor, nKeys);
  k_fillR<<<rangedGrid, 256, 0, stream>>>(ei, et, yk, cursor, bucket, nE, rsz);

  // ---- layer 1 (fused agg+GEMM+stats) ----
  k_fused<<<fusedBlocks, 256, 0, stream>>>(entbf, rfb, offsets, bucket, WT1,
                                           Cb, rep1, M);
  k_collapse<<<1, 256, 0, stream>>>(rep1, fin1);
  k_norm<<<normBlocks, 256, 0, stream>>>((const uint4*)Cb, fin1, fin1 + 128, g1, b1,
                                         1.0f / M, (uint4*)xb, nQuad);

  // ---- layer 2 ----
  k_fused<<<fusedBlocks, 256, 0, stream>>>(xb, r1b, offsets, bucket, WT2,
                                           Cb, rep2, M);
  k_collapse<<<1, 256, 0, stream>>>(rep2, fin2);
  k_norm<<<normBlocks, 256, 0, stream>>>((const uint4*)Cb, fin2, fin2 + 128, g2, b2,
                                         1.0f / M, (uint4*)xb, nQuad);

  // ---- scoring ----
  k_score<<<(nT * 64 + 255) / 256, 256, 0, stream>>>(xb, r2, triples, out, nT);
}

// Round 9
// 399.518 us; speedup vs baseline: 2.4889x; 1.1362x over previous
//
#include <hip/hip_runtime.h>
#include <cstdint>

typedef __attribute__((ext_vector_type(8))) short short8;
typedef __attribute__((ext_vector_type(4))) float f32x4;

static __device__ __forceinline__ unsigned short f2bf(float f) {
  unsigned int u = __float_as_uint(f);
  unsigned int r = (u + 0x7FFFu + ((u >> 16) & 1u)) >> 16;   // RNE
  return (unsigned short)r;
}
static __device__ __forceinline__ unsigned int pack2bf(float a, float b) {
  return (unsigned int)f2bf(a) | ((unsigned int)f2bf(b) << 16);
}
static __device__ __forceinline__ float2 bf2f(unsigned int u) {
  return make_float2(__uint_as_float(u << 16), __uint_as_float(u & 0xFFFF0000u));
}
static __device__ __forceinline__ void acc8(float* a, uint4 h, uint4 r) {
  float2 f, g;
  f = bf2f(h.x); g = bf2f(r.x); a[0] += f.x - g.x; a[1] += f.y - g.y;
  f = bf2f(h.y); g = bf2f(r.y); a[2] += f.x - g.x; a[3] += f.y - g.y;
  f = bf2f(h.z); g = bf2f(r.z); a[4] += f.x - g.x; a[5] += f.y - g.y;
  f = bf2f(h.w); g = bf2f(r.w); a[6] += f.x - g.x; a[7] += f.y - g.y;
}

// ---- one-shot prep kernel (R5-verified) ----
__global__ __launch_bounds__(256) void k_prep(
    const float* __restrict__ coeff, const float* __restrict__ bases,
    const float* __restrict__ selfr, const float* __restrict__ relw1,
    const float* __restrict__ relw2,
    unsigned int* __restrict__ rfb, unsigned int* __restrict__ r1b,
    float* __restrict__ r2,
    const float* __restrict__ W1, const float* __restrict__ W2,
    unsigned short* __restrict__ WT1, unsigned short* __restrict__ WT2,
    const float* __restrict__ ent, const int* __restrict__ ent_ids,
    unsigned int* __restrict__ entbf,
    int* __restrict__ counts, float* __restrict__ stats,
    int nPairs, int nKeys, int cvtB, int cntB) {
  int b = blockIdx.x, tid = threadIdx.x;
  if (b < 201) {
    __shared__ float row[2][128], r1row[2][128];
    int half = tid >> 7, c = tid & 127;
    int r = 2 * b + half;
    bool ok = (r <= 400);
    if (ok) {
      float v;
      if (r == 400) {
        v = selfr[c];
      } else {
        int rr = (r < 200) ? r : r - 200;
        float s = 0.f;
#pragma unroll 10
        for (int k = 0; k < 50; ++k) s += coeff[rr * 50 + k] * bases[k * 128 + c];
        v = (r < 200) ? s : -s;
      }
      row[half][c] = v;
    }
    __syncthreads();
    if (ok && c < 64) rfb[r * 64 + c] = pack2bf(row[half][2 * c], row[half][2 * c + 1]);
    if (ok) {
      float s = 0.f;
#pragma unroll 8
      for (int k = 0; k < 128; ++k) s += row[half][k] * relw1[k * 128 + c];
      r1row[half][c] = s;
    }
    __syncthreads();
    if (ok && c < 64) r1b[r * 64 + c] = pack2bf(r1row[half][2 * c], r1row[half][2 * c + 1]);
    if (ok) {
      float s = 0.f;
#pragma unroll 8
      for (int k = 0; k < 128; ++k) s += r1row[half][k] * relw2[k * 128 + c];
      r2[r * 128 + c] = s;
    }
  } else if (b < 585) {
    int idx = (b - 201) * 256 + tid;
    const int half = 128 * 384;
    const float* W = (idx < half) ? W1 : W2;
    unsigned short* WT = (idx < half) ? WT1 : WT2;
    int id2 = (idx < half) ? idx : idx - half;
    int n = id2 & 127, k = id2 >> 7;
    int kk = k >> 7, kr = k & 127;
    WT[(size_t)n * 384 + k] = f2bf(W[(size_t)kk * 16384 + kr * 128 + n]);
  } else if (b < 585 + cvtB) {
    int i = (b - 585) * 256 + tid;
    if (i < nPairs) {
      int e = i >> 6;
      int src = ent_ids[e];
      float2 v = *(const float2*)&ent[(size_t)src * 128 + (i & 63) * 2];
      entbf[i] = pack2bf(v.x, v.y);
    }
  } else if (b < 585 + cvtB + cntB) {
    int i = (b - (585 + cvtB)) * 256 + tid;
    if (i < nKeys) counts[i] = 0;
  } else {
    int i = (b - (585 + cvtB + cntB)) * 256 + tid;
    if (i < 16896) stats[i] = 0.f;
  }
}

// ---- CSR build (unchanged, range-partitioned) ----
__global__ __launch_bounds__(256) void k_histR(const int* __restrict__ ei, const int* __restrict__ y,
                                               int* __restrict__ counts, int nE, int rsz) {
  int r = blockIdx.x;
  int e0 = blockIdx.y * 1024;
#pragma unroll
  for (int i = 0; i < 4; ++i) {
    int e = e0 + i * 256 + threadIdx.x;
    if (e < nE) {
      int key = ei[nE + e] * 3 + y[e];
      if (key / rsz == r) atomicAdd(&counts[key], 1);
    }
  }
}

__global__ void k_scan1(const int* __restrict__ counts, int* __restrict__ local,
                        int* __restrict__ blockSums, int n) {
  __shared__ int sdata[1024];
  int tid = threadIdx.x;
  int i = blockIdx.x * 1024 + tid;
  int v = (i < n) ? counts[i] : 0;
  sdata[tid] = v;
  __syncthreads();
  for (int off = 1; off < 1024; off <<= 1) {
    int t = (tid >= off) ? sdata[tid - off] : 0;
    __syncthreads();
    sdata[tid] += t;
    __syncthreads();
  }
  if (i < n) local[i] = sdata[tid] - v;
  if (tid == 1023) blockSums[blockIdx.x] = sdata[1023];
}

__global__ void k_scan2(const int* __restrict__ blockSums, int* __restrict__ carries,
                        int* __restrict__ offsets, int n, int nb) {
  __shared__ int sdata[1024];
  int tid = threadIdx.x;
  int v = (tid < nb) ? blockSums[tid] : 0;
  sdata[tid] = v;
  __syncthreads();
  for (int off = 1; off < 1024; off <<= 1) {
    int t = (tid >= off) ? sdata[tid - off] : 0;
    __syncthreads();
    sdata[tid] += t;
    __syncthreads();
  }
  if (tid < nb) carries[tid] = sdata[tid] - v;
  if (tid == 1023) offsets[n] = sdata[1023];
}

__global__ void k_scan3(const int* __restrict__ local, const int* __restrict__ carries,
                        int* __restrict__ offsets, int* __restrict__ cursor, int n) {
  int i = blockIdx.x * 1024 + threadIdx.x;
  if (i >= n) return;
  int v = local[i] + carries[blockIdx.x];
  offsets[i] = v;
  cursor[i] = v;
}

__global__ __launch_bounds__(256) void k_fillR(const int* __restrict__ ei, const int* __restrict__ et,
                                               const int* __restrict__ y, int* __restrict__ cursor,
                                               unsigned int* __restrict__ bucket, int nE, int rsz) {
  int r = blockIdx.x;
  int e0 = blockIdx.y * 1024;
#pragma unroll
  for (int i = 0; i < 4; ++i) {
    int e = e0 + i * 256 + threadIdx.x;
    if (e < nE) {
      int key = ei[nE + e] * 3 + y[e];
      if (key / rsz == r) {
        int slot = atomicAdd(&cursor[key], 1);
        bucket[slot] = (unsigned int)ei[e] | ((unsigned int)et[e] << 20);
      }
    }
  }
}

// ---- FUSED gather-aggregate + GEMM + BN-stats, BM=32 (R5 geometry).
// R9 change: the 6 class-segments of a quad's 2 dst rows are CONTIGUOUS in
// bucket -> walk them as one edge stream with a depth-2 software pipeline
// (prefetch edges j+2,j+3, clamped/branchless, while accumulating j,j+1),
// flushing the fp32 accumulator to LDS at segment boundaries.  Boundaries
// live in named registers (select chain, no runtime-indexed array ->
// no scratch).  Removes the per-segment pipeline stall that limited the
// latency-bound gather to ~1.3 loads in flight (R8 lesson: mean segment
// is 2.67 edges, so per-segment ILP never engages).
__global__ __launch_bounds__(256, 6) void k_fused(
    const unsigned int* __restrict__ xb, const unsigned int* __restrict__ rb,
    const int* __restrict__ offsets, const unsigned int* __restrict__ packed,
    const unsigned short* __restrict__ WT, unsigned short* __restrict__ C,
    float* __restrict__ statsRep, int M) {
  __shared__ unsigned short As[32][392];
  __shared__ float sSum[128], sSq[128];
  const int tid = threadIdx.x;
  const int m0 = blockIdx.x * 32;
  const int wave = tid >> 6, lane = tid & 63;
  const int quad = lane >> 4, l16 = lane & 15;
  const int qid = (wave << 2) | quad;          // 0..15: rows 2qid, 2qid+1
  if (tid < 128) { sSum[tid] = 0.f; sSq[tid] = 0.f; }

  // ---- gather phase: contiguous edge walk over 6 segments ----
  {
    const int dst0 = m0 + 2 * qid;
    int b0, b1, b2, b3, b4, b5, b6;
    if (dst0 + 1 < M) {
      const int base = dst0 * 3;
      b0 = offsets[base];     b1 = offsets[base + 1];
      b2 = offsets[base + 2]; b3 = offsets[base + 3];
      b4 = offsets[base + 4]; b5 = offsets[base + 5];
      b6 = offsets[base + 6];
    } else if (dst0 < M) {
      const int base = dst0 * 3;
      b0 = offsets[base];     b1 = offsets[base + 1];
      b2 = offsets[base + 2]; b3 = offsets[base + 3];
      b4 = b3; b5 = b3; b6 = b3;
    } else {
      b0 = b1 = b2 = b3 = b4 = b5 = b6 = 0;
    }
    float ac[8] = {};
    int seg = 0;
    int nextB = b1;
    int j = b0;
    const int hi = b6;
    unsigned short* lds0 = &As[2 * qid][0];

    auto flushSeg = [&]() {
      int rowOff = (seg >= 3) ? 392 : 0;
      int cls = seg - ((seg >= 3) ? 3 : 0);
      uint4 ov;
      ov.x = pack2bf(ac[0], ac[1]);
      ov.y = pack2bf(ac[2], ac[3]);
      ov.z = pack2bf(ac[4], ac[5]);
      ov.w = pack2bf(ac[6], ac[7]);
      *(uint4*)(lds0 + rowOff + cls * 128 + l16 * 8) = ov;
#pragma unroll
      for (int z = 0; z < 8; ++z) ac[z] = 0.f;
      ++seg;
      nextB = (seg == 1) ? b2 : (seg == 2) ? b3 : (seg == 3) ? b4
            : (seg == 4) ? b5 : b6;
    };

    if (j < hi) {
      // preload edges j, j+1 (clamped)
      int jc1 = (j + 1 < hi) ? j + 1 : j;
      unsigned int q0 = packed[j], q1 = packed[jc1];
      int s0 = q0 & 0xFFFFF, t0 = q0 >> 20;
      int s1 = q1 & 0xFFFFF, t1 = q1 >> 20;
      uint4 h0 = *(const uint4*)&xb[(size_t)s0 * 64 + l16 * 4];
      uint4 r0 = *(const uint4*)&rb[(size_t)t0 * 64 + l16 * 4];
      uint4 h1 = *(const uint4*)&xb[(size_t)s1 * 64 + l16 * 4];
      uint4 r1 = *(const uint4*)&rb[(size_t)t1 * 64 + l16 * 4];
      while (j < hi) {
        // branchless prefetch of edges j+2, j+3 (clamped to hi-1)
        int jp2 = (j + 2 < hi) ? j + 2 : hi - 1;
        int jp3 = (j + 3 < hi) ? j + 3 : hi - 1;
        unsigned int q2 = packed[jp2], q3 = packed[jp3];
        int s2 = q2 & 0xFFFFF, t2 = q2 >> 20;
        int s3 = q3 & 0xFFFFF, t3 = q3 >> 20;
        uint4 th0 = *(const uint4*)&xb[(size_t)s2 * 64 + l16 * 4];
        uint4 tr0 = *(const uint4*)&rb[(size_t)t2 * 64 + l16 * 4];
        uint4 th1 = *(const uint4*)&xb[(size_t)s3 * 64 + l16 * 4];
        uint4 tr1 = *(const uint4*)&rb[(size_t)t3 * 64 + l16 * 4];
        // consume edge j
        while (j == nextB) flushSeg();
        acc8(ac, h0, r0);
        ++j;
        if (j < hi) {
          while (j == nextB) flushSeg();
          acc8(ac, h1, r1);
          ++j;
        }
        h0 = th0; r0 = tr0; h1 = th1; r1 = tr1;
      }
    }
    // drain remaining (possibly empty) segments
    while (seg < 6) flushSeg();
  }
  __syncthreads();

  // ---- GEMM phase: C[32x128] = As[32x384] @ WT^T, B streamed from L2 ----
  const unsigned short* Wp = WT + (size_t)(wave * 32 + l16) * 384 + quad * 8;
  short8 bc0 = *(const short8*)(Wp);
  short8 bc1 = *(const short8*)(Wp + 16 * 384);
  f32x4 acc[2][2] = {};
#pragma unroll 1
  for (int it = 0; it < 12; ++it) {
    short8 bn0, bn1;
    if (it < 11) {
      bn0 = *(const short8*)(Wp + (it + 1) * 32);
      bn1 = *(const short8*)(Wp + 16 * 384 + (it + 1) * 32);
    }
    short8 a0 = *(const short8*)&As[l16][it * 32 + quad * 8];
    short8 a1 = *(const short8*)&As[16 + l16][it * 32 + quad * 8];
    acc[0][0] = __builtin_amdgcn_mfma_f32_16x16x32_bf16(a0, bc0, acc[0][0], 0, 0, 0);
    acc[0][1] = __builtin_amdgcn_mfma_f32_16x16x32_bf16(a0, bc1, acc[0][1], 0, 0, 0);
    acc[1][0] = __builtin_amdgcn_mfma_f32_16x16x32_bf16(a1, bc0, acc[1][0], 0, 0, 0);
    acc[1][1] = __builtin_amdgcn_mfma_f32_16x16x32_bf16(a1, bc1, acc[1][1], 0, 0, 0);
    if (it < 11) { bc0 = bn0; bc1 = bn1; }
  }

  // ---- epilogue: bf16 C store + BN stats (replicated atomics) ----
  float ps[2] = {}, pq[2] = {};
#pragma unroll
  for (int t = 0; t < 2; ++t)
#pragma unroll
    for (int reg = 0; reg < 4; ++reg) {
      int m = m0 + t * 16 + quad * 4 + reg;
      if (m < M) {
#pragma unroll
        for (int ct = 0; ct < 2; ++ct) {
          float v = acc[t][ct][reg];
          int col = wave * 32 + ct * 16 + l16;
          C[(size_t)m * 128 + col] = f2bf(v);
          ps[ct] += v; pq[ct] += v * v;
        }
      }
    }
#pragma unroll
  for (int ct = 0; ct < 2; ++ct) {
    int col = wave * 32 + ct * 16 + l16;
    atomicAdd(&sSum[col], ps[ct]);
    atomicAdd(&sSq[col], pq[ct]);
  }
  __syncthreads();
  if (tid < 128) {
    float* rep = statsRep + ((blockIdx.x & 31) << 8);
    atomicAdd(&rep[tid], sSum[tid]);
    atomicAdd(&rep[128 + tid], sSq[tid]);
  }
}

// norm + tanh, uint4-vectorized; folds the 32-replica stat collapse inline
// (replica region is 32KB, L2-hot; saves the separate k_collapse dispatch)
__global__ void k_norm(const uint4* __restrict__ Cb4, const float* __restrict__ rep,
                       const float* __restrict__ gamma, const float* __restrict__ beta,
                       float invN, uint4* __restrict__ xb4, int nQuad) {
  __shared__ float sc_s[128], bi_s[128];
  if (threadIdx.x < 128) {
    int c = threadIdx.x;
    float s = 0.f, q = 0.f;
#pragma unroll
    for (int r = 0; r < 32; ++r) {
      s += rep[r * 256 + c];
      q += rep[r * 256 + 128 + c];
    }
    float mean = s * invN;
    float var = fmaxf(q * invN - mean * mean, 0.f);
    float sc = rsqrtf(var + 1e-5f) * gamma[c];
    sc_s[c] = sc;
    bi_s[c] = beta[c] - mean * sc;
  }
  __syncthreads();
  int i = blockIdx.x * blockDim.x + threadIdx.x;
  if (i >= nQuad) return;
  uint4 v = Cb4[i];
  int j = (i * 4) & 63;
  uint4 o;
  float2 f;
  f = bf2f(v.x);
  o.x = pack2bf(tanhf(fmaf(f.x, sc_s[2*j],   bi_s[2*j])),   tanhf(fmaf(f.y, sc_s[2*j+1], bi_s[2*j+1])));
  f = bf2f(v.y);
  o.y = pack2bf(tanhf(fmaf(f.x, sc_s[2*j+2], bi_s[2*j+2])), tanhf(fmaf(f.y, sc_s[2*j+3], bi_s[2*j+3])));
  f = bf2f(v.z);
  o.z = pack2bf(tanhf(fmaf(f.x, sc_s[2*j+4], bi_s[2*j+4])), tanhf(fmaf(f.y, sc_s[2*j+5], bi_s[2*j+5])));
  f = bf2f(v.w);
  o.w = pack2bf(tanhf(fmaf(f.x, sc_s[2*j+6], bi_s[2*j+6])), tanhf(fmaf(f.y, sc_s[2*j+7], bi_s[2*j+7])));
  xb4[i] = o;
}

// one wave per triple: sum_d |x[h]+r[rel]-x[t]|
__global__ void k_score(const unsigned int* __restrict__ xb, const float* __restrict__ r,
                        const int* __restrict__ triples, float* __restrict__ out, int nT) {
  int gid = blockIdx.x * blockDim.x + threadIdx.x;
  int t = gid >> 6;
  if (t >= nT) return;
  int lane = gid & 63;
  int h = triples[t * 3], rel = triples[t * 3 + 1], tl = triples[t * 3 + 2];
  float2 a = bf2f(xb[(size_t)h * 64 + lane]);
  float2 b = *(const float2*)&r[(size_t)rel * 128 + lane * 2];
  float2 cc = bf2f(xb[(size_t)tl * 64 + lane]);
  float s = fabsf(a.x + b.x - cc.x) + fabsf(a.y + b.y - cc.y);
#pragma unroll
  for (int off = 32; off > 0; off >>= 1) s += __shfl_down(s, off);
  if (lane == 0) out[t] = s;
}

extern "C" void kernel_launch(void* const* d_in, const int* in_sizes, int n_in,
                              void* d_out, int out_size, void* d_ws, size_t ws_size,
                              hipStream_t stream) {
  const float* ent   = (const float*)d_in[0];
  const float* bases = (const float*)d_in[1];
  const float* coeff = (const float*)d_in[2];
  const float* selfr = (const float*)d_in[3];
  const float* W1    = (const float*)d_in[4];
  const float* relw1 = (const float*)d_in[5];
  const float* g1    = (const float*)d_in[6];
  const float* b1    = (const float*)d_in[7];
  const float* W2    = (const float*)d_in[8];
  const float* relw2 = (const float*)d_in[9];
  const float* g2    = (const float*)d_in[10];
  const float* b2    = (const float*)d_in[11];
  const int* ent_ids = (const int*)d_in[12];
  const int* ei      = (const int*)d_in[13];
  const int* et      = (const int*)d_in[14];
  const int* yk      = (const int*)d_in[15];
  const int* triples = (const int*)d_in[16];

  const int M  = in_sizes[0] / 128;   // 100000
  const int nE = in_sizes[14];        // 800000
  const int nT = in_sizes[16] / 3;    // 4096
  const int nKeys = M * 3;
  const int nScanBlocks = (nKeys + 1023) / 1024;
  const int rsz = (nKeys + 7) / 8;

  // workspace layout (~88 MB)
  float* p = (float*)d_ws;
  float* r2    = p; p += 401 * 128;
  float* statsAll = p; p += 16896;     // rep1(32x256) | rep2(32x256) | spare
  float* rep1 = statsAll;
  float* rep2 = statsAll + 32 * 256;
  unsigned short* Cb  = (unsigned short*)p;                       // M*128 bf16
  unsigned int* entbf = (unsigned int*)(Cb + (size_t)M * 128);    // M*64
  unsigned int* xb    = entbf + (size_t)M * 64;                   // M*64
  unsigned int* rfb   = xb + (size_t)M * 64;                      // 401*64
  unsigned int* r1b   = rfb + 401 * 64;                           // 401*64
  unsigned short* WT1 = (unsigned short*)(r1b + 401 * 64);
  unsigned short* WT2 = WT1 + 128 * 384;
  int* counts  = (int*)(WT2 + 128 * 384);
  int* offsets = counts + nKeys;
  int* cursor  = offsets + nKeys + 1;
  int* slocal  = cursor + nKeys;
  int* sblock  = slocal + nKeys;
  int* scarry  = sblock + nScanBlocks;
  unsigned int* bucket = (unsigned int*)(scarry + nScanBlocks);

  float* out = (float*)d_out;

  const int nPairs = M * 64;
  const int nQuad  = M * 16;
  const int cvtB = (nPairs + 255) / 256;
  const int cntB = (nKeys + 255) / 256;
  const int zeroB = 66;
  const int prepBlocks = 585 + cvtB + cntB + zeroB;
  const int fusedBlocks = (M + 31) / 32;
  const int normBlocks = (nQuad + 255) / 256;
  const dim3 rangedGrid(8, (nE + 1023) / 1024);

  k_prep<<<prepBlocks, 256, 0, stream>>>(coeff, bases, selfr, relw1, relw2,
                                         rfb, r1b, r2, W1, W2, WT1, WT2,
                                         ent, ent_ids, entbf, counts, statsAll,
                                         nPairs, nKeys, cvtB, cntB);

  // CSR over (dst, class)
  k_histR<<<rangedGrid, 256, 0, stream>>>(ei, yk, counts, nE, rsz);
  k_scan1<<<nScanBlocks, 1024, 0, stream>>>(counts, slocal, sblock, nKeys);
  k_scan2<<<1, 1024, 0, stream>>>(sblock, scarry, offsets, nKeys, nScanBlocks);
  k_scan3<<<nScanBlocks, 1024, 0, stream>>>(slocal, scarry, offsets, cursor, nKeys);
  k_fillR<<<rangedGrid, 256, 0, stream>>>(ei, et, yk, cursor, bucket, nE, rsz);

  // ---- layer 1 (fused agg+GEMM+stats) ----
  k_fused<<<fusedBlocks, 256, 0, stream>>>(entbf, rfb, offsets, bucket, WT1,
                                           Cb, rep1, M);
  k_norm<<<normBlocks, 256, 0, stream>>>((const uint4*)Cb, rep1, g1, b1,
                                         1.0f / M, (uint4*)xb, nQuad);

  // ---- layer 2 ----
  k_fused<<<fusedBlocks, 256, 0, stream>>>(xb, r1b, offsets, bucket, WT2,
                                           Cb, rep2, M);
  k_norm<<<normBlocks, 256, 0, stream>>>((const uint4*)Cb, rep2, g2, b2,
                                         1.0f / M, (uint4*)xb, nQuad);

  // ---- scoring ----
  k_score<<<(nT * 64 + 255) / 256, 256, 0, stream>>>(xb, r2, triples, out, nT);
}